// Round 1
// baseline (1196.174 us; speedup 1.0000x reference)
//
#include <hip/hip_runtime.h>
#include <hip/hip_bf16.h>
#include <cstddef>
#include <cstdint>

#define CAP 40
#define LEAK 0.01f

// ---------------------------------------------------------------------------
// Bucket build: for each edge e, dst=ei[e], src=ei[E+e]; append src to dst's
// bucket. cnt[] must be zeroed before. cnt ends up == in-degree(dst).
// ---------------------------------------------------------------------------
__global__ void build_buckets(const int* __restrict__ ei, int E_,
                              int* __restrict__ cnt, int* __restrict__ bucket) {
    int e = blockIdx.x * 256 + threadIdx.x;
    if (e >= E_) return;
    int dst = ei[e];
    int src = ei[(size_t)E_ + e];
    int pos = atomicAdd(&cnt[dst], 1);
    if (pos < CAP) bucket[(size_t)dst * CAP + pos] = src;
}

__global__ void invdeg_k(const int* __restrict__ cnt, float* __restrict__ invd, int Nn) {
    int i = blockIdx.x * 256 + threadIdx.x;
    if (i < Nn) invd[i] = 1.0f / (float)(cnt[i] + 1);
}

// ---------------------------------------------------------------------------
// GEMM: C[M x 128] = act(A[M x 128] @ W[128 x 128] + bias)
// ACT: 0 = none, 1 = leaky relu, 2 = sigmoid
// Block: 256 threads, 64 rows x 128 cols tile. W + X tile staged in LDS.
// Per thread: 8 rows x 4 cols micro-tile, all LDS reads are b128.
// ---------------------------------------------------------------------------
template <int ACT>
__global__ __launch_bounds__(256) void gemm128(const float* __restrict__ A,
                                               const float* __restrict__ W,
                                               const float* __restrict__ bias,
                                               float* __restrict__ Cout, int M) {
    __shared__ float Ws[128 * 128];
    __shared__ float Xs[64 * 128];
    const int tid = threadIdx.x;
    {
        const float4* Wg = (const float4*)W;
        float4* Wl = (float4*)Ws;
#pragma unroll
        for (int i = 0; i < 16; ++i) Wl[i * 256 + tid] = Wg[i * 256 + tid];
    }
    const int row0 = blockIdx.x * 64;
    const int nrow = min(64, M - row0);
    {
        const float4* Ag = (const float4*)(A + (size_t)row0 * 128);
        float4* Xl = (float4*)Xs;
        for (int i = tid; i < nrow * 32; i += 256) Xl[i] = Ag[i];
    }
    __syncthreads();

    const int ct = (tid & 31) * 4;  // col offset
    const int rt = (tid >> 5) * 8;  // row offset within tile
    float acc[8][4];
#pragma unroll
    for (int r = 0; r < 8; ++r) {
        acc[r][0] = 0.f; acc[r][1] = 0.f; acc[r][2] = 0.f; acc[r][3] = 0.f;
    }

    for (int k = 0; k < 128; k += 4) {
        float4 w0 = *(const float4*)&Ws[(k + 0) * 128 + ct];
        float4 w1 = *(const float4*)&Ws[(k + 1) * 128 + ct];
        float4 w2 = *(const float4*)&Ws[(k + 2) * 128 + ct];
        float4 w3 = *(const float4*)&Ws[(k + 3) * 128 + ct];
#pragma unroll
        for (int r = 0; r < 8; ++r) {
            float4 xv = *(const float4*)&Xs[(rt + r) * 128 + k];
            acc[r][0] = fmaf(xv.w, w3.x, fmaf(xv.z, w2.x, fmaf(xv.y, w1.x, fmaf(xv.x, w0.x, acc[r][0]))));
            acc[r][1] = fmaf(xv.w, w3.y, fmaf(xv.z, w2.y, fmaf(xv.y, w1.y, fmaf(xv.x, w0.y, acc[r][1]))));
            acc[r][2] = fmaf(xv.w, w3.z, fmaf(xv.z, w2.z, fmaf(xv.y, w1.z, fmaf(xv.x, w0.z, acc[r][2]))));
            acc[r][3] = fmaf(xv.w, w3.w, fmaf(xv.z, w2.w, fmaf(xv.y, w1.w, fmaf(xv.x, w0.w, acc[r][3]))));
        }
    }

    float4 bv = *(const float4*)&bias[ct];
#pragma unroll
    for (int r = 0; r < 8; ++r) {
        int row = row0 + rt + r;
        if (row < M) {
            float4 v;
            v.x = acc[r][0] + bv.x;
            v.y = acc[r][1] + bv.y;
            v.z = acc[r][2] + bv.z;
            v.w = acc[r][3] + bv.w;
            if (ACT == 1) {
                v.x = v.x > 0.f ? v.x : LEAK * v.x;
                v.y = v.y > 0.f ? v.y : LEAK * v.y;
                v.z = v.z > 0.f ? v.z : LEAK * v.z;
                v.w = v.w > 0.f ? v.w : LEAK * v.w;
            } else if (ACT == 2) {
                v.x = 1.f / (1.f + expf(-v.x));
                v.y = 1.f / (1.f + expf(-v.y));
                v.z = 1.f / (1.f + expf(-v.z));
                v.w = 1.f / (1.f + expf(-v.w));
            }
            *(float4*)&Cout[(size_t)row * 128 + ct] = v;
        }
    }
}

// ---------------------------------------------------------------------------
// Aggregate: xout[i] = (h[i] + sum_{j in bucket[i]} h[j]) * invd[i]
// One wave (64 lanes) per node; lane handles 2 floats (float2 = 8B/lane).
// ---------------------------------------------------------------------------
__global__ __launch_bounds__(256) void aggregate(const float* __restrict__ h,
                                                 const int* __restrict__ bucket,
                                                 const int* __restrict__ cnt,
                                                 const float* __restrict__ invd,
                                                 float* __restrict__ xout, int Nn) {
    int node = blockIdx.x * 4 + (threadIdx.x >> 6);
    if (node >= Nn) return;
    int lane = threadIdx.x & 63;
    size_t base = (size_t)node * 128 + lane * 2;
    float2 acc = *(const float2*)&h[base];
    int d = min(cnt[node], CAP);
    const int* bk = bucket + (size_t)node * CAP;
    for (int j = 0; j < d; ++j) {
        int s = bk[j];
        float2 v = *(const float2*)&h[(size_t)s * 128 + lane * 2];
        acc.x += v.x;
        acc.y += v.y;
    }
    float id = invd[node];
    acc.x *= id;
    acc.y *= id;
    *(float2*)&xout[base] = acc;
}

// ---------------------------------------------------------------------------
// Elementwise multiply (gate): o = a * b
// ---------------------------------------------------------------------------
__global__ void mul_ew(const float4* __restrict__ a, const float4* __restrict__ b,
                       float4* __restrict__ o, int n4) {
    int i = blockIdx.x * 256 + threadIdx.x;
    if (i < n4) {
        float4 x = a[i], y = b[i];
        float4 r;
        r.x = x.x * y.x; r.y = x.y * y.y; r.z = x.z * y.z; r.w = x.w * y.w;
        o[i] = r;
    }
}

// ---------------------------------------------------------------------------
// Exclusive-scan num_atoms -> goff[G+1]. Single block, G <= 1024.
// ---------------------------------------------------------------------------
__global__ void scan_atoms(const int* __restrict__ na, int* __restrict__ goff, int G_) {
    __shared__ int sh[1024];
    int t = threadIdx.x;
    int v = (t < G_) ? na[t] : 0;
    sh[t] = v;
    __syncthreads();
    for (int ofs = 1; ofs < 1024; ofs <<= 1) {
        int u = (t >= ofs) ? sh[t - ofs] : 0;
        __syncthreads();
        sh[t] += u;
        __syncthreads();
    }
    if (t == 0) goff[0] = 0;
    if (t < G_) goff[t + 1] = sh[t];
}

// ---------------------------------------------------------------------------
// Graph mean-pool: gattr[g][d] = mean over nodes [goff[g], goff[g+1]) of x[.][d]
// One block (128 threads) per graph.
// ---------------------------------------------------------------------------
__global__ void pool(const float* __restrict__ x, const int* __restrict__ goff,
                     float* __restrict__ gattr, int G_) {
    int g = blockIdx.x;
    int d = threadIdx.x;
    int a0 = goff[g], a1 = goff[g + 1];
    float s = 0.f;
    for (int a = a0; a < a1; ++a) s += x[(size_t)a * 128 + d];
    float c = (float)max(a1 - a0, 1);
    gattr[(size_t)g * 128 + d] = s / c;
}

// ---------------------------------------------------------------------------
// Final: out[g][c] = gattr[g] @ fin_W[:,c] + fin_b[c]   (C = 10)
// ---------------------------------------------------------------------------
__global__ void final_gemm(const float* __restrict__ gattr, const float* __restrict__ fW,
                           const float* __restrict__ fb, float* __restrict__ out,
                           int G_, int C_) {
    int i = blockIdx.x * 256 + threadIdx.x;
    if (i >= G_ * C_) return;
    int g = i / C_, c = i % C_;
    const float* row = gattr + (size_t)g * 128;
    float s = fb[c];
    for (int k = 0; k < 128; ++k) s = fmaf(row[k], fW[k * C_ + c], s);
    out[i] = s;
}

// ---------------------------------------------------------------------------
extern "C" void kernel_launch(void* const* d_in, const int* in_sizes, int n_in,
                              void* d_out, int out_size, void* d_ws, size_t ws_size,
                              hipStream_t stream) {
    const float* node_attr = (const float*)d_in[0];
    const int* edge_index  = (const int*)d_in[1];   // int inputs arrive as int32
    const int* num_atoms   = (const int*)d_in[2];
    const float* enc_W = (const float*)d_in[3];
    const float* enc_b = (const float*)d_in[4];
    const float* gcn_W = (const float*)d_in[5];
    const float* gcn_b = (const float*)d_in[6];
    const float* r_W1 = (const float*)d_in[7];
    const float* r_b1 = (const float*)d_in[8];
    const float* r_W2 = (const float*)d_in[9];
    const float* r_b2 = (const float*)d_in[10];
    const float* s_W1 = (const float*)d_in[11];
    const float* s_b1 = (const float*)d_in[12];
    const float* s_W2 = (const float*)d_in[13];
    const float* s_b2 = (const float*)d_in[14];
    const float* fin_W = (const float*)d_in[15];
    const float* fin_b = (const float*)d_in[16];
    float* out = (float*)d_out;

    const int N_ = in_sizes[0] / 128;
    const int E_ = in_sizes[1] / 2;
    const int G_ = in_sizes[2];
    const int C_ = in_sizes[16];

    // workspace carve-up
    size_t off = 0;
    auto alloc = [&](size_t bytes) -> void* {
        void* p = (char*)d_ws + off;
        off += (bytes + 255) & ~(size_t)255;
        return p;
    };
    float* bx   = (float*)alloc((size_t)N_ * 128 * 4);
    float* bh   = (float*)alloc((size_t)N_ * 128 * 4);
    float* b2   = (float*)alloc((size_t)N_ * 128 * 4);
    int* bucket = (int*)alloc((size_t)N_ * CAP * 4);
    int* cnt    = (int*)alloc((size_t)N_ * 4);
    float* invd = (float*)alloc((size_t)N_ * 4);
    int* goff   = (int*)alloc((size_t)(G_ + 1) * 4);
    float* gattr = (float*)alloc((size_t)G_ * 128 * 4);
    (void)ws_size; (void)n_in; (void)out_size;

    const int gemm_grid = (N_ + 63) / 64;

    // 1. degree buckets
    hipMemsetAsync(cnt, 0, (size_t)N_ * 4, stream);
    build_buckets<<<(E_ + 255) / 256, 256, 0, stream>>>(edge_index, E_, cnt, bucket);
    invdeg_k<<<(N_ + 255) / 256, 256, 0, stream>>>(cnt, invd, N_);
    scan_atoms<<<1, 1024, 0, stream>>>(num_atoms, goff, G_);

    // 2. encoder
    gemm128<0><<<gemm_grid, 256, 0, stream>>>(node_attr, enc_W, enc_b, bx, N_);

    // 3. GCN layers
    for (int l = 0; l < 4; ++l) {
        gemm128<0><<<gemm_grid, 256, 0, stream>>>(bx, gcn_W + (size_t)l * 128 * 128,
                                                  gcn_b + (size_t)l * 128, bh, N_);
        aggregate<<<(N_ + 3) / 4, 256, 0, stream>>>(bh, bucket, cnt, invd, bx, N_);
    }

    // 4. GateMLP:  r = leaky(leaky(x@rW1+b)@rW2+b);  g = sigmoid(leaky(x@sW1+b)@sW2+b)
    gemm128<1><<<gemm_grid, 256, 0, stream>>>(bx, r_W1, r_b1, bh, N_);
    gemm128<1><<<gemm_grid, 256, 0, stream>>>(bh, r_W2, r_b2, b2, N_);  // r -> b2
    gemm128<1><<<gemm_grid, 256, 0, stream>>>(bx, s_W1, s_b1, bh, N_);
    gemm128<2><<<gemm_grid, 256, 0, stream>>>(bh, s_W2, s_b2, bx, N_);  // g -> bx
    mul_ew<<<(N_ * 32 + 255) / 256, 256, 0, stream>>>((const float4*)b2, (const float4*)bx,
                                                      (float4*)bh, N_ * 32);

    // 5. pool + final
    pool<<<G_, 128, 0, stream>>>(bh, goff, gattr, G_);
    final_gemm<<<(G_ * C_ + 255) / 256, 256, 0, stream>>>(gattr, fin_W, fin_b, out, G_, C_);
}

// Round 2
// 604.579 us; speedup vs baseline: 1.9785x; 1.9785x over previous
//
#include <hip/hip_runtime.h>
#include <hip/hip_bf16.h>
#include <cstddef>
#include <cstdint>

#define CAP 40
#define LEAK 0.01f

typedef __attribute__((ext_vector_type(8))) short short8v;
typedef __attribute__((ext_vector_type(4))) float float4v;

__device__ __forceinline__ unsigned short f2bf(float f) {
    uint32_t u = __float_as_uint(f);
    uint32_t r = (u + 0x7FFFu + ((u >> 16) & 1u)) >> 16;   // RNE
    return (unsigned short)r;
}
__device__ __forceinline__ float bf2f(unsigned short s) {
    return __uint_as_float(((uint32_t)s) << 16);
}

// ---------------------------------------------------------------------------
// Bucket build: append src to dst's bucket; cnt ends as in-degree(dst).
// ---------------------------------------------------------------------------
__global__ void build_buckets(const int* __restrict__ ei, int E_,
                              int* __restrict__ cnt, int* __restrict__ bucket) {
    int e = blockIdx.x * 256 + threadIdx.x;
    if (e >= E_) return;
    int dst = ei[e];
    int src = ei[(size_t)E_ + e];
    int pos = atomicAdd(&cnt[dst], 1);
    if (pos < CAP) bucket[(size_t)dst * CAP + pos] = src;
}

__global__ void invdeg_k(const int* __restrict__ cnt, float* __restrict__ invd, int Nn) {
    int i = blockIdx.x * 256 + threadIdx.x;
    if (i < Nn) invd[i] = 1.0f / (float)(cnt[i] + 1);
}

// ---------------------------------------------------------------------------
// MFMA GEMM: C[M x 128](bf16) = act(A[M x 128] @ W[128 x 128] + bias) [* Rgate]
// A: fp32 (INF32) or bf16. W,bias fp32. ACT: 0 none, 1 leaky, 2 sigmoid.
// Block 256 thr = 4 waves; tile 64 rows x 128 cols; wave w owns cols w*32..+31.
// W frags held in registers (loaded from global, L2-hot). A staged in 16KB LDS
// bf16 with XOR swizzle byte^=((row&7)<<4) for conflict-reduced ds_read_b128.
// MFMA 16x16x32 bf16: A/B lane map {m|n = lane&15, k = (lane>>4)*8+j},
// C/D lane map {col = lane&15, row = (lane>>4)*4+reg} (verified m89).
// ---------------------------------------------------------------------------
template <int ACT, bool INF32, bool GATE>
__global__ __launch_bounds__(256) void gemm_mfma(const void* __restrict__ Ain,
                                                 const float* __restrict__ W,
                                                 const float* __restrict__ bias,
                                                 const unsigned short* __restrict__ Rgate,
                                                 unsigned short* __restrict__ Cout,
                                                 int M) {
    __shared__ unsigned short As[64 * 128];  // swizzled bf16 tile
    const int tid = threadIdx.x;
    const int lane = tid & 63;
    const int w = tid >> 6;
    const int row0 = blockIdx.x * 64;
    const int fr = lane & 15;
    const int fg = lane >> 4;

    // ---- W fragments: wf[t][kc], t = n-tile (w*32 + t*16), kc = K/32 chunk ----
    short8v wf[2][4];
    {
        const int n = w * 32 + fr;
#pragma unroll
        for (int t = 0; t < 2; ++t) {
            const float* Wp = W + n + t * 16;
#pragma unroll
            for (int kc = 0; kc < 4; ++kc) {
                short8v v;
#pragma unroll
                for (int j = 0; j < 8; ++j) {
                    float f = Wp[(size_t)(kc * 32 + fg * 8 + j) * 128];
                    v[j] = (short)f2bf(f);
                }
                wf[t][kc] = v;
            }
        }
    }

    // ---- stage A tile (64 rows x 128 cols) into LDS as bf16, swizzled ----
    {
        const int r = tid >> 2;       // 0..63
        const int cg = tid & 3;       // 32-col group
        const int row = row0 + r;
        char* lbase = (char*)As + r * 256;
        if (INF32) {
            const float* Ap = (const float*)Ain + (size_t)row * 128 + cg * 32;
#pragma unroll
            for (int i = 0; i < 4; ++i) {
                short8v v = {0, 0, 0, 0, 0, 0, 0, 0};
                if (row < M) {
                    float4v p = *(const float4v*)(Ap + i * 8);
                    float4v q = *(const float4v*)(Ap + i * 8 + 4);
                    v[0] = (short)f2bf(p[0]); v[1] = (short)f2bf(p[1]);
                    v[2] = (short)f2bf(p[2]); v[3] = (short)f2bf(p[3]);
                    v[4] = (short)f2bf(q[0]); v[5] = (short)f2bf(q[1]);
                    v[6] = (short)f2bf(q[2]); v[7] = (short)f2bf(q[3]);
                }
                int cb = (cg * 64 + i * 16) ^ ((r & 7) << 4);
                *(short8v*)(lbase + cb) = v;
            }
        } else {
            const unsigned short* Ap = (const unsigned short*)Ain + (size_t)row * 128 + cg * 32;
#pragma unroll
            for (int i = 0; i < 4; ++i) {
                short8v v = {0, 0, 0, 0, 0, 0, 0, 0};
                if (row < M) v = *(const short8v*)(Ap + i * 8);
                int cb = (cg * 64 + i * 16) ^ ((r & 7) << 4);
                *(short8v*)(lbase + cb) = v;
            }
        }
    }
    __syncthreads();

    // ---- K loop: 4 chunks of K=32 ----
    float4v acc[4][2];
#pragma unroll
    for (int m = 0; m < 4; ++m) {
        acc[m][0] = (float4v){0.f, 0.f, 0.f, 0.f};
        acc[m][1] = (float4v){0.f, 0.f, 0.f, 0.f};
    }
#pragma unroll
    for (int kc = 0; kc < 4; ++kc) {
        short8v a[4];
#pragma unroll
        for (int m = 0; m < 4; ++m) {
            int row = m * 16 + fr;
            int cb = (kc * 64 + fg * 16) ^ ((row & 7) << 4);
            a[m] = *(const short8v*)((const char*)As + row * 256 + cb);
        }
#pragma unroll
        for (int m = 0; m < 4; ++m) {
            acc[m][0] = __builtin_amdgcn_mfma_f32_16x16x32_bf16(a[m], wf[0][kc], acc[m][0], 0, 0, 0);
            acc[m][1] = __builtin_amdgcn_mfma_f32_16x16x32_bf16(a[m], wf[1][kc], acc[m][1], 0, 0, 0);
        }
    }

    // ---- epilogue ----
#pragma unroll
    for (int t = 0; t < 2; ++t) {
        const int col = w * 32 + t * 16 + fr;
        const float bv = bias[col];
#pragma unroll
        for (int m = 0; m < 4; ++m) {
#pragma unroll
            for (int q = 0; q < 4; ++q) {
                int row = row0 + m * 16 + fg * 4 + q;
                if (row < M) {
                    float v = acc[m][t][q] + bv;
                    if (ACT == 1) v = v > 0.f ? v : LEAK * v;
                    else if (ACT == 2) v = 1.f / (1.f + __expf(-v));
                    if (GATE) v *= bf2f(Rgate[(size_t)row * 128 + col]);
                    Cout[(size_t)row * 128 + col] = f2bf(v);
                }
            }
        }
    }
}

// ---------------------------------------------------------------------------
// Aggregate (bf16): xout[i] = (h[i] + sum_{j in bucket[i]} h[j]) * invd[i]
// One wave per node; lane holds 2 bf16 (one dword).
// ---------------------------------------------------------------------------
__global__ __launch_bounds__(256) void aggregate_bf16(const unsigned short* __restrict__ h,
                                                      const int* __restrict__ bucket,
                                                      const int* __restrict__ cnt,
                                                      const float* __restrict__ invd,
                                                      unsigned short* __restrict__ xout,
                                                      int Nn) {
    int node = blockIdx.x * 4 + (threadIdx.x >> 6);
    if (node >= Nn) return;
    int lane = threadIdx.x & 63;
    const uint32_t* hp = (const uint32_t*)h;
    uint32_t u = hp[(size_t)node * 64 + lane];
    float ax = bf2f((unsigned short)(u & 0xffff));
    float ay = bf2f((unsigned short)(u >> 16));
    int d = min(cnt[node], CAP);
    d = __builtin_amdgcn_readfirstlane(d);
    const int* bk = bucket + (size_t)node * CAP;
    for (int j = 0; j < d; ++j) {
        int s = __builtin_amdgcn_readfirstlane(bk[j]);
        uint32_t v = hp[(size_t)s * 64 + lane];
        ax += bf2f((unsigned short)(v & 0xffff));
        ay += bf2f((unsigned short)(v >> 16));
    }
    float id = invd[node];
    ax *= id;
    ay *= id;
    uint32_t o = (uint32_t)f2bf(ax) | ((uint32_t)f2bf(ay) << 16);
    ((uint32_t*)xout)[(size_t)node * 64 + lane] = o;
}

// ---------------------------------------------------------------------------
// Exclusive-scan num_atoms -> goff[G+1]. Single block, G <= 1024.
// ---------------------------------------------------------------------------
__global__ void scan_atoms(const int* __restrict__ na, int* __restrict__ goff, int G_) {
    __shared__ int sh[1024];
    int t = threadIdx.x;
    int v = (t < G_) ? na[t] : 0;
    sh[t] = v;
    __syncthreads();
    for (int ofs = 1; ofs < 1024; ofs <<= 1) {
        int u = (t >= ofs) ? sh[t - ofs] : 0;
        __syncthreads();
        sh[t] += u;
        __syncthreads();
    }
    if (t == 0) goff[0] = 0;
    if (t < G_) goff[t + 1] = sh[t];
}

// ---------------------------------------------------------------------------
// Graph mean-pool from bf16 x. One block (128 threads) per graph.
// ---------------------------------------------------------------------------
__global__ void pool(const unsigned short* __restrict__ x, const int* __restrict__ goff,
                     float* __restrict__ gattr, int G_) {
    int g = blockIdx.x;
    int d = threadIdx.x;
    int a0 = goff[g], a1 = goff[g + 1];
    float s = 0.f;
    for (int a = a0; a < a1; ++a) s += bf2f(x[(size_t)a * 128 + d]);
    float c = (float)max(a1 - a0, 1);
    gattr[(size_t)g * 128 + d] = s / c;
}

// ---------------------------------------------------------------------------
// Final: out[g][c] = gattr[g] @ fin_W[:,c] + fin_b[c]   (C = 10), fp32.
// ---------------------------------------------------------------------------
__global__ void final_gemm(const float* __restrict__ gattr, const float* __restrict__ fW,
                           const float* __restrict__ fb, float* __restrict__ out,
                           int G_, int C_) {
    int i = blockIdx.x * 256 + threadIdx.x;
    if (i >= G_ * C_) return;
    int g = i / C_, c = i % C_;
    const float* row = gattr + (size_t)g * 128;
    float s = fb[c];
    for (int k = 0; k < 128; ++k) s = fmaf(row[k], fW[k * C_ + c], s);
    out[i] = s;
}

// ---------------------------------------------------------------------------
extern "C" void kernel_launch(void* const* d_in, const int* in_sizes, int n_in,
                              void* d_out, int out_size, void* d_ws, size_t ws_size,
                              hipStream_t stream) {
    const float* node_attr = (const float*)d_in[0];
    const int* edge_index  = (const int*)d_in[1];
    const int* num_atoms   = (const int*)d_in[2];
    const float* enc_W = (const float*)d_in[3];
    const float* enc_b = (const float*)d_in[4];
    const float* gcn_W = (const float*)d_in[5];
    const float* gcn_b = (const float*)d_in[6];
    const float* r_W1 = (const float*)d_in[7];
    const float* r_b1 = (const float*)d_in[8];
    const float* r_W2 = (const float*)d_in[9];
    const float* r_b2 = (const float*)d_in[10];
    const float* s_W1 = (const float*)d_in[11];
    const float* s_b1 = (const float*)d_in[12];
    const float* s_W2 = (const float*)d_in[13];
    const float* s_b2 = (const float*)d_in[14];
    const float* fin_W = (const float*)d_in[15];
    const float* fin_b = (const float*)d_in[16];
    float* out = (float*)d_out;

    const int N_ = in_sizes[0] / 128;
    const int E_ = in_sizes[1] / 2;
    const int G_ = in_sizes[2];
    const int C_ = in_sizes[16];

    size_t off = 0;
    auto alloc = [&](size_t bytes) -> void* {
        void* p = (char*)d_ws + off;
        off += (bytes + 255) & ~(size_t)255;
        return p;
    };
    unsigned short* bx = (unsigned short*)alloc((size_t)N_ * 128 * 2);
    unsigned short* bh = (unsigned short*)alloc((size_t)N_ * 128 * 2);
    unsigned short* b2 = (unsigned short*)alloc((size_t)N_ * 128 * 2);
    int* bucket = (int*)alloc((size_t)N_ * CAP * 4);
    int* cnt    = (int*)alloc((size_t)N_ * 4);
    float* invd = (float*)alloc((size_t)N_ * 4);
    int* goff   = (int*)alloc((size_t)(G_ + 1) * 4);
    float* gattr = (float*)alloc((size_t)G_ * 128 * 4);
    (void)ws_size; (void)n_in; (void)out_size;

    const int gemm_grid = (N_ + 63) / 64;
    const int agg_grid = (N_ + 3) / 4;

    // 1. degree buckets + graph offsets
    hipMemsetAsync(cnt, 0, (size_t)N_ * 4, stream);
    build_buckets<<<(E_ + 255) / 256, 256, 0, stream>>>(edge_index, E_, cnt, bucket);
    invdeg_k<<<(N_ + 255) / 256, 256, 0, stream>>>(cnt, invd, N_);
    scan_atoms<<<1, 1024, 0, stream>>>(num_atoms, goff, G_);

    // 2. encoder (fp32 in -> bf16 out)
    gemm_mfma<0, true, false><<<gemm_grid, 256, 0, stream>>>(node_attr, enc_W, enc_b,
                                                             nullptr, bx, N_);

    // 3. GCN layers
    for (int l = 0; l < 4; ++l) {
        gemm_mfma<0, false, false><<<gemm_grid, 256, 0, stream>>>(
            bx, gcn_W + (size_t)l * 128 * 128, gcn_b + (size_t)l * 128, nullptr, bh, N_);
        aggregate_bf16<<<agg_grid, 256, 0, stream>>>(bh, bucket, cnt, invd, bx, N_);
    }

    // 4. GateMLP: r = leaky(leaky(x@rW1)@rW2); out = sigmoid(leaky(x@sW1)@sW2) * r
    gemm_mfma<1, false, false><<<gemm_grid, 256, 0, stream>>>(bx, r_W1, r_b1, nullptr, bh, N_);
    gemm_mfma<1, false, false><<<gemm_grid, 256, 0, stream>>>(bh, r_W2, r_b2, nullptr, b2, N_);
    gemm_mfma<1, false, false><<<gemm_grid, 256, 0, stream>>>(bx, s_W1, s_b1, nullptr, bh, N_);
    gemm_mfma<2, false, true><<<gemm_grid, 256, 0, stream>>>(bh, s_W2, s_b2, b2, bx, N_);

    // 5. pool + final
    pool<<<G_, 128, 0, stream>>>(bx, goff, gattr, G_);
    final_gemm<<<(G_ * C_ + 255) / 256, 256, 0, stream>>>(gattr, fin_W, fin_b, out, G_, C_);
}

// Round 3
// 392.466 us; speedup vs baseline: 3.0478x; 1.5405x over previous
//
#include <hip/hip_runtime.h>
#include <hip/hip_bf16.h>
#include <cstddef>
#include <cstdint>

#define CAP 40
#define LEAK 0.01f

typedef __attribute__((ext_vector_type(8))) short short8v;
typedef __attribute__((ext_vector_type(4))) float float4v;

__device__ __forceinline__ unsigned short f2bf(float f) {
    uint32_t u = __float_as_uint(f);
    uint32_t r = (u + 0x7FFFu + ((u >> 16) & 1u)) >> 16;   // RNE
    return (unsigned short)r;
}
__device__ __forceinline__ float bf2f(unsigned short s) {
    return __uint_as_float(((uint32_t)s) << 16);
}

// ---------------------------------------------------------------------------
// Bucket build: append src to dst's bucket; cnt ends as in-degree(dst).
// ---------------------------------------------------------------------------
__global__ void build_buckets(const int* __restrict__ ei, int E_,
                              int* __restrict__ cnt, int* __restrict__ bucket) {
    int e = blockIdx.x * 256 + threadIdx.x;
    if (e >= E_) return;
    int dst = ei[e];
    int src = ei[(size_t)E_ + e];
    int pos = atomicAdd(&cnt[dst], 1);
    if (pos < CAP) bucket[(size_t)dst * CAP + pos] = src;
}

// ---------------------------------------------------------------------------
// Pack 9 fp32 [128x128] weight matrices into bf16 MFMA-fragment order:
// p[m][((kc*4+fg)*128 + n)*8 + j] = bf16(W_m[(kc*32+fg*8+j)*128 + n])
// One thread per (kc,fg,n) = 2048 threads per matrix; grid = 9*8 blocks.
// ---------------------------------------------------------------------------
__global__ void pack_w(const float* __restrict__ enc, const float* __restrict__ gcn,
                       const float* __restrict__ rw1, const float* __restrict__ rw2,
                       const float* __restrict__ sw1, const float* __restrict__ sw2,
                       unsigned short* __restrict__ p) {
    int m = blockIdx.x >> 3;
    int idx = (blockIdx.x & 7) * 256 + threadIdx.x;   // 0..2047
    const float* W;
    switch (m) {
        case 0: W = enc; break;
        case 1: case 2: case 3: case 4: W = gcn + (size_t)(m - 1) * 16384; break;
        case 5: W = rw1; break;
        case 6: W = rw2; break;
        case 7: W = sw1; break;
        default: W = sw2; break;
    }
    int n = idx & 127;
    int fg = (idx >> 7) & 3;
    int kc = idx >> 9;
    short8v v;
#pragma unroll
    for (int j = 0; j < 8; ++j)
        v[j] = (short)f2bf(W[(size_t)(kc * 32 + fg * 8 + j) * 128 + n]);
    *(short8v*)(p + (size_t)m * 16384 + (size_t)idx * 8) = v;
}

// ---------------------------------------------------------------------------
// MFMA GEMM: C[M x 128](bf16) = act(A[M x 128] @ W[128 x 128] + bias) [* Rgate]
// A: fp32 (INF32) or bf16. Wpack: bf16 fragment-ordered. ACT: 0/1/2.
// Block 256 thr = 4 waves; tile 64 rows x 128 cols; wave w owns cols w*32..+31.
// A staged in 16KB LDS bf16 with XOR swizzle byte^=((row&7)<<4).
// ---------------------------------------------------------------------------
template <int ACT, bool INF32, bool GATE>
__global__ __launch_bounds__(256) void gemm_mfma(const void* __restrict__ Ain,
                                                 const unsigned short* __restrict__ Wpack,
                                                 const float* __restrict__ bias,
                                                 const unsigned short* __restrict__ Rgate,
                                                 unsigned short* __restrict__ Cout,
                                                 int M) {
    __shared__ unsigned short As[64 * 128];  // swizzled bf16 tile
    const int tid = threadIdx.x;
    const int lane = tid & 63;
    const int w = tid >> 6;
    const int row0 = blockIdx.x * 64;
    const int fr = lane & 15;
    const int fg = lane >> 4;

    // ---- W fragments from packed buffer: 8 x dwordx4, coalesced ----
    short8v wf[2][4];
    {
        const short8v* Wp = (const short8v*)Wpack;
#pragma unroll
        for (int t = 0; t < 2; ++t)
#pragma unroll
            for (int kc = 0; kc < 4; ++kc)
                wf[t][kc] = Wp[(kc * 4 + fg) * 128 + w * 32 + t * 16 + fr];
    }

    // ---- stage A tile (64 rows x 128 cols) into LDS as bf16, swizzled ----
    {
        const int r = tid >> 2;       // 0..63
        const int cg = tid & 3;       // 32-col group
        const int row = row0 + r;
        char* lbase = (char*)As + r * 256;
        if (INF32) {
            const float* Ap = (const float*)Ain + (size_t)row * 128 + cg * 32;
#pragma unroll
            for (int i = 0; i < 4; ++i) {
                short8v v = {0, 0, 0, 0, 0, 0, 0, 0};
                if (row < M) {
                    float4v p = *(const float4v*)(Ap + i * 8);
                    float4v q = *(const float4v*)(Ap + i * 8 + 4);
                    v[0] = (short)f2bf(p[0]); v[1] = (short)f2bf(p[1]);
                    v[2] = (short)f2bf(p[2]); v[3] = (short)f2bf(p[3]);
                    v[4] = (short)f2bf(q[0]); v[5] = (short)f2bf(q[1]);
                    v[6] = (short)f2bf(q[2]); v[7] = (short)f2bf(q[3]);
                }
                int cb = (cg * 64 + i * 16) ^ ((r & 7) << 4);
                *(short8v*)(lbase + cb) = v;
            }
        } else {
            const unsigned short* Ap = (const unsigned short*)Ain + (size_t)row * 128 + cg * 32;
#pragma unroll
            for (int i = 0; i < 4; ++i) {
                short8v v = {0, 0, 0, 0, 0, 0, 0, 0};
                if (row < M) v = *(const short8v*)(Ap + i * 8);
                int cb = (cg * 64 + i * 16) ^ ((r & 7) << 4);
                *(short8v*)(lbase + cb) = v;
            }
        }
    }
    __syncthreads();

    // ---- K loop: 4 chunks of K=32 ----
    float4v acc[4][2];
#pragma unroll
    for (int m = 0; m < 4; ++m) {
        acc[m][0] = (float4v){0.f, 0.f, 0.f, 0.f};
        acc[m][1] = (float4v){0.f, 0.f, 0.f, 0.f};
    }
#pragma unroll
    for (int kc = 0; kc < 4; ++kc) {
        short8v a[4];
#pragma unroll
        for (int m = 0; m < 4; ++m) {
            int row = m * 16 + fr;
            int cb = (kc * 64 + fg * 16) ^ ((row & 7) << 4);
            a[m] = *(const short8v*)((const char*)As + row * 256 + cb);
        }
#pragma unroll
        for (int m = 0; m < 4; ++m) {
            acc[m][0] = __builtin_amdgcn_mfma_f32_16x16x32_bf16(a[m], wf[0][kc], acc[m][0], 0, 0, 0);
            acc[m][1] = __builtin_amdgcn_mfma_f32_16x16x32_bf16(a[m], wf[1][kc], acc[m][1], 0, 0, 0);
        }
    }

    // ---- epilogue ----
#pragma unroll
    for (int t = 0; t < 2; ++t) {
        const int col = w * 32 + t * 16 + fr;
        const float bv = bias[col];
#pragma unroll
        for (int m = 0; m < 4; ++m) {
#pragma unroll
            for (int q = 0; q < 4; ++q) {
                int row = row0 + m * 16 + fg * 4 + q;
                if (row < M) {
                    float v = acc[m][t][q] + bv;
                    if (ACT == 1) v = v > 0.f ? v : LEAK * v;
                    else if (ACT == 2) v = 1.f / (1.f + __expf(-v));
                    if (GATE) v *= bf2f(Rgate[(size_t)row * 128 + col]);
                    Cout[(size_t)row * 128 + col] = f2bf(v);
                }
            }
        }
    }
}

// ---------------------------------------------------------------------------
// Aggregate (bf16): xout[i] = (h[i] + sum_{j in bucket[i]} h[j]) / (deg[i]+1)
// 2 nodes per wave (32 lanes x 8 B per row). Bucket indices preloaded into
// lane registers and broadcast via shfl; j-loop unrolled x4 with predicated
// accumulation for 4-deep memory-level parallelism.
// ---------------------------------------------------------------------------
__global__ __launch_bounds__(256) void aggregate_bf16(const unsigned short* __restrict__ h,
                                                      const int* __restrict__ bucket,
                                                      const int* __restrict__ cnt,
                                                      unsigned short* __restrict__ xout,
                                                      int Nn) {
    const int lane = threadIdx.x & 63;
    const int wid = blockIdx.x * 4 + (threadIdx.x >> 6);
    const int half = lane >> 5;
    const int hl = lane & 31;
    int node = wid * 2 + half;
    const bool alive = node < Nn;
    if (!alive) node = Nn - 1;

    const int c = cnt[node];
    const float id = 1.0f / (float)(c + 1);
    const int d = min(c, CAP);

    int idxv = 0;
    if (hl < d) idxv = bucket[(size_t)node * CAP + hl];   // slots 0..min(d,32)-1

    const uint32_t* hp = (const uint32_t*)h;
    const size_t rbase = (size_t)node * 64 + hl * 2;
    uint2 u = *(const uint2*)&hp[rbase];
    float a0 = bf2f((unsigned short)(u.x & 0xffff));
    float a1 = bf2f((unsigned short)(u.x >> 16));
    float a2 = bf2f((unsigned short)(u.y & 0xffff));
    float a3 = bf2f((unsigned short)(u.y >> 16));

    const int dmax = max(d, __shfl(d, lane ^ 32));
    const int lbase = half << 5;
    const int dm32 = min(dmax, 32);
    for (int j = 0; j < dm32; j += 4) {
        int s0 = __shfl(idxv, lbase + j);
        int s1 = __shfl(idxv, lbase + j + 1);
        int s2 = __shfl(idxv, lbase + j + 2);
        int s3 = __shfl(idxv, lbase + j + 3);
        uint2 v0 = *(const uint2*)&hp[(size_t)s0 * 64 + hl * 2];
        uint2 v1 = *(const uint2*)&hp[(size_t)s1 * 64 + hl * 2];
        uint2 v2 = *(const uint2*)&hp[(size_t)s2 * 64 + hl * 2];
        uint2 v3 = *(const uint2*)&hp[(size_t)s3 * 64 + hl * 2];
        float m0 = (j + 0 < d) ? 1.f : 0.f;
        float m1 = (j + 1 < d) ? 1.f : 0.f;
        float m2 = (j + 2 < d) ? 1.f : 0.f;
        float m3 = (j + 3 < d) ? 1.f : 0.f;
        a0 = fmaf(m0, bf2f((unsigned short)(v0.x & 0xffff)), a0);
        a1 = fmaf(m0, bf2f((unsigned short)(v0.x >> 16)), a1);
        a2 = fmaf(m0, bf2f((unsigned short)(v0.y & 0xffff)), a2);
        a3 = fmaf(m0, bf2f((unsigned short)(v0.y >> 16)), a3);
        a0 = fmaf(m1, bf2f((unsigned short)(v1.x & 0xffff)), a0);
        a1 = fmaf(m1, bf2f((unsigned short)(v1.x >> 16)), a1);
        a2 = fmaf(m1, bf2f((unsigned short)(v1.y & 0xffff)), a2);
        a3 = fmaf(m1, bf2f((unsigned short)(v1.y >> 16)), a3);
        a0 = fmaf(m2, bf2f((unsigned short)(v2.x & 0xffff)), a0);
        a1 = fmaf(m2, bf2f((unsigned short)(v2.x >> 16)), a1);
        a2 = fmaf(m2, bf2f((unsigned short)(v2.y & 0xffff)), a2);
        a3 = fmaf(m2, bf2f((unsigned short)(v2.y >> 16)), a3);
        a0 = fmaf(m3, bf2f((unsigned short)(v3.x & 0xffff)), a0);
        a1 = fmaf(m3, bf2f((unsigned short)(v3.x >> 16)), a1);
        a2 = fmaf(m3, bf2f((unsigned short)(v3.y & 0xffff)), a2);
        a3 = fmaf(m3, bf2f((unsigned short)(v3.y >> 16)), a3);
    }
    // ultra-rare tail: in-degree beyond 32 (Poisson(6.4) => ~never)
    for (int j = 32; j < d; ++j) {
        int s = bucket[(size_t)node * CAP + j];
        uint2 v = *(const uint2*)&hp[(size_t)s * 64 + hl * 2];
        a0 += bf2f((unsigned short)(v.x & 0xffff));
        a1 += bf2f((unsigned short)(v.x >> 16));
        a2 += bf2f((unsigned short)(v.y & 0xffff));
        a3 += bf2f((unsigned short)(v.y >> 16));
    }

    a0 *= id; a1 *= id; a2 *= id; a3 *= id;
    if (alive) {
        uint2 o;
        o.x = (uint32_t)f2bf(a0) | ((uint32_t)f2bf(a1) << 16);
        o.y = (uint32_t)f2bf(a2) | ((uint32_t)f2bf(a3) << 16);
        *(uint2*)&((uint32_t*)xout)[rbase] = o;
    }
}

// ---------------------------------------------------------------------------
// Exclusive-scan num_atoms -> goff[G+1]. Single block, G <= 1024.
// ---------------------------------------------------------------------------
__global__ void scan_atoms(const int* __restrict__ na, int* __restrict__ goff, int G_) {
    __shared__ int sh[1024];
    int t = threadIdx.x;
    int v = (t < G_) ? na[t] : 0;
    sh[t] = v;
    __syncthreads();
    for (int ofs = 1; ofs < 1024; ofs <<= 1) {
        int u = (t >= ofs) ? sh[t - ofs] : 0;
        __syncthreads();
        sh[t] += u;
        __syncthreads();
    }
    if (t == 0) goff[0] = 0;
    if (t < G_) goff[t + 1] = sh[t];
}

// ---------------------------------------------------------------------------
// Graph mean-pool from bf16 x. One block (128 threads) per graph.
// ---------------------------------------------------------------------------
__global__ void pool(const unsigned short* __restrict__ x, const int* __restrict__ goff,
                     float* __restrict__ gattr, int G_) {
    int g = blockIdx.x;
    int d = threadIdx.x;
    int a0 = goff[g], a1 = goff[g + 1];
    float s = 0.f;
    for (int a = a0; a < a1; ++a) s += bf2f(x[(size_t)a * 128 + d]);
    float c = (float)max(a1 - a0, 1);
    gattr[(size_t)g * 128 + d] = s / c;
}

// ---------------------------------------------------------------------------
// Final: out[g][c] = gattr[g] @ fin_W[:,c] + fin_b[c]   (C = 10), fp32.
// ---------------------------------------------------------------------------
__global__ void final_gemm(const float* __restrict__ gattr, const float* __restrict__ fW,
                           const float* __restrict__ fb, float* __restrict__ out,
                           int G_, int C_) {
    int i = blockIdx.x * 256 + threadIdx.x;
    if (i >= G_ * C_) return;
    int g = i / C_, c = i % C_;
    const float* row = gattr + (size_t)g * 128;
    float s = fb[c];
    for (int k = 0; k < 128; ++k) s = fmaf(row[k], fW[k * C_ + c], s);
    out[i] = s;
}

// ---------------------------------------------------------------------------
extern "C" void kernel_launch(void* const* d_in, const int* in_sizes, int n_in,
                              void* d_out, int out_size, void* d_ws, size_t ws_size,
                              hipStream_t stream) {
    const float* node_attr = (const float*)d_in[0];
    const int* edge_index  = (const int*)d_in[1];
    const int* num_atoms   = (const int*)d_in[2];
    const float* enc_W = (const float*)d_in[3];
    const float* enc_b = (const float*)d_in[4];
    const float* gcn_W = (const float*)d_in[5];
    const float* gcn_b = (const float*)d_in[6];
    const float* r_W1 = (const float*)d_in[7];
    const float* r_b1 = (const float*)d_in[8];
    const float* r_W2 = (const float*)d_in[9];
    const float* r_b2 = (const float*)d_in[10];
    const float* s_W1 = (const float*)d_in[11];
    const float* s_b1 = (const float*)d_in[12];
    const float* s_W2 = (const float*)d_in[13];
    const float* s_b2 = (const float*)d_in[14];
    const float* fin_W = (const float*)d_in[15];
    const float* fin_b = (const float*)d_in[16];
    float* out = (float*)d_out;

    const int N_ = in_sizes[0] / 128;
    const int E_ = in_sizes[1] / 2;
    const int G_ = in_sizes[2];
    const int C_ = in_sizes[16];

    size_t off = 0;
    auto alloc = [&](size_t bytes) -> void* {
        void* p = (char*)d_ws + off;
        off += (bytes + 255) & ~(size_t)255;
        return p;
    };
    unsigned short* bx = (unsigned short*)alloc((size_t)N_ * 128 * 2);
    unsigned short* bh = (unsigned short*)alloc((size_t)N_ * 128 * 2);
    unsigned short* b2 = (unsigned short*)alloc((size_t)N_ * 128 * 2);
    int* bucket = (int*)alloc((size_t)N_ * CAP * 4);
    int* cnt    = (int*)alloc((size_t)N_ * 4);
    unsigned short* wpack = (unsigned short*)alloc((size_t)9 * 16384 * 2);
    int* goff   = (int*)alloc((size_t)(G_ + 1) * 4);
    float* gattr = (float*)alloc((size_t)G_ * 128 * 4);
    (void)ws_size; (void)n_in; (void)out_size;

    const int gemm_grid = (N_ + 63) / 64;
    const int agg_grid = (N_ + 7) / 8;

    // 1. degree buckets + weight packing + graph offsets
    hipMemsetAsync(cnt, 0, (size_t)N_ * 4, stream);
    build_buckets<<<(E_ + 255) / 256, 256, 0, stream>>>(edge_index, E_, cnt, bucket);
    pack_w<<<72, 256, 0, stream>>>(enc_W, gcn_W, r_W1, r_W2, s_W1, s_W2, wpack);
    scan_atoms<<<1, 1024, 0, stream>>>(num_atoms, goff, G_);

    // 2. encoder (fp32 in -> bf16 out)
    gemm_mfma<0, true, false><<<gemm_grid, 256, 0, stream>>>(node_attr, wpack, enc_b,
                                                             nullptr, bx, N_);

    // 3. GCN layers
    for (int l = 0; l < 4; ++l) {
        gemm_mfma<0, false, false><<<gemm_grid, 256, 0, stream>>>(
            bx, wpack + (size_t)(1 + l) * 16384, gcn_b + (size_t)l * 128, nullptr, bh, N_);
        aggregate_bf16<<<agg_grid, 256, 0, stream>>>(bh, bucket, cnt, bx, N_);
    }

    // 4. GateMLP: r = leaky(leaky(x@rW1)@rW2); out = sigmoid(leaky(x@sW1)@sW2) * r
    gemm_mfma<1, false, false><<<gemm_grid, 256, 0, stream>>>(bx, wpack + (size_t)5 * 16384, r_b1, nullptr, bh, N_);
    gemm_mfma<1, false, false><<<gemm_grid, 256, 0, stream>>>(bh, wpack + (size_t)6 * 16384, r_b2, nullptr, b2, N_);
    gemm_mfma<1, false, false><<<gemm_grid, 256, 0, stream>>>(bx, wpack + (size_t)7 * 16384, s_b1, nullptr, bh, N_);
    gemm_mfma<2, false, true><<<gemm_grid, 256, 0, stream>>>(bh, wpack + (size_t)8 * 16384, s_b2, b2, bx, N_);

    // 5. pool + final
    pool<<<G_, 128, 0, stream>>>(bx, goff, gattr, G_);
    final_gemm<<<(G_ * C_ + 255) / 256, 256, 0, stream>>>(gattr, fin_W, fin_b, out, G_, C_);
}

// Round 4
// 348.904 us; speedup vs baseline: 3.4284x; 1.1249x over previous
//
#include <hip/hip_runtime.h>
#include <hip/hip_bf16.h>
#include <cstddef>
#include <cstdint>

#define CAP 40
#define LEAK 0.01f

typedef __attribute__((ext_vector_type(8))) short short8v;
typedef __attribute__((ext_vector_type(4))) float float4v;

__device__ __forceinline__ unsigned short f2bf(float f) {
    uint32_t u = __float_as_uint(f);
    uint32_t r = (u + 0x7FFFu + ((u >> 16) & 1u)) >> 16;   // RNE
    return (unsigned short)r;
}
__device__ __forceinline__ float bf2f(unsigned short s) {
    return __uint_as_float(((uint32_t)s) << 16);
}

// ---------------------------------------------------------------------------
// Bucket build, 2 edges/thread (int2 loads): append src to dst's bucket.
// cnt ends as in-degree(dst).
// ---------------------------------------------------------------------------
__global__ void build_buckets(const int* __restrict__ ei, int E_,
                              int* __restrict__ cnt, int* __restrict__ bucket) {
    int e = (blockIdx.x * 256 + threadIdx.x) * 2;
    if (e >= E_) return;
    if (e + 1 < E_) {
        int2 d2 = *(const int2*)&ei[e];
        int2 s2 = *(const int2*)&ei[(size_t)E_ + e];
        int p0 = atomicAdd(&cnt[d2.x], 1);
        if (p0 < CAP) bucket[(size_t)d2.x * CAP + p0] = s2.x;
        int p1 = atomicAdd(&cnt[d2.y], 1);
        if (p1 < CAP) bucket[(size_t)d2.y * CAP + p1] = s2.y;
    } else {
        int d = ei[e], s = ei[(size_t)E_ + e];
        int p = atomicAdd(&cnt[d], 1);
        if (p < CAP) bucket[(size_t)d * CAP + p] = s;
    }
}

// ---------------------------------------------------------------------------
// Pack 9 fp32 [128x128] weight matrices into bf16 MFMA-fragment order:
// p[m][((kc*4+fg)*128 + n)*8 + j] = bf16(W_m[(kc*32+fg*8+j)*128 + n])
// ---------------------------------------------------------------------------
__global__ void pack_w(const float* __restrict__ enc, const float* __restrict__ gcn,
                       const float* __restrict__ rw1, const float* __restrict__ rw2,
                       const float* __restrict__ sw1, const float* __restrict__ sw2,
                       unsigned short* __restrict__ p) {
    int m = blockIdx.x >> 3;
    int idx = (blockIdx.x & 7) * 256 + threadIdx.x;   // 0..2047
    const float* W;
    switch (m) {
        case 0: W = enc; break;
        case 1: case 2: case 3: case 4: W = gcn + (size_t)(m - 1) * 16384; break;
        case 5: W = rw1; break;
        case 6: W = rw2; break;
        case 7: W = sw1; break;
        default: W = sw2; break;
    }
    int n = idx & 127;
    int fg = (idx >> 7) & 3;
    int kc = idx >> 9;
    short8v v;
#pragma unroll
    for (int j = 0; j < 8; ++j)
        v[j] = (short)f2bf(W[(size_t)(kc * 32 + fg * 8 + j) * 128 + n]);
    *(short8v*)(p + (size_t)m * 16384 + (size_t)idx * 8) = v;
}

// ---------------------------------------------------------------------------
// Shared MFMA helpers. LDS tile layout: 64 rows x 128 bf16 cols, 256 B/row,
// byte offset within row XOR-swizzled by ((row&7)<<4).
// A-frag {m=lane&15, k=(lane>>4)*8+j}; B-frag {n=lane&15, k=(lane>>4)*8+j};
// C/D {col=lane&15, row=(lane>>4)*4+reg}.
// ---------------------------------------------------------------------------
__device__ __forceinline__ void load_wf(const unsigned short* __restrict__ Wpack,
                                        int w, int fr, int fg, short8v wf[2][4]) {
    const short8v* Wp = (const short8v*)Wpack;
#pragma unroll
    for (int t = 0; t < 2; ++t)
#pragma unroll
        for (int kc = 0; kc < 4; ++kc)
            wf[t][kc] = Wp[(kc * 4 + fg) * 128 + w * 32 + t * 16 + fr];
}

__device__ __forceinline__ void mfma_tile(const unsigned short* As, int fr, int fg,
                                          const short8v wf[2][4], float4v acc[4][2]) {
#pragma unroll
    for (int m = 0; m < 4; ++m) {
        acc[m][0] = (float4v){0.f, 0.f, 0.f, 0.f};
        acc[m][1] = (float4v){0.f, 0.f, 0.f, 0.f};
    }
#pragma unroll
    for (int kc = 0; kc < 4; ++kc) {
        short8v a[4];
#pragma unroll
        for (int m = 0; m < 4; ++m) {
            int row = m * 16 + fr;
            int cb = (kc * 64 + fg * 16) ^ ((row & 7) << 4);
            a[m] = *(const short8v*)((const char*)As + row * 256 + cb);
        }
#pragma unroll
        for (int m = 0; m < 4; ++m) {
            acc[m][0] = __builtin_amdgcn_mfma_f32_16x16x32_bf16(a[m], wf[0][kc], acc[m][0], 0, 0, 0);
            acc[m][1] = __builtin_amdgcn_mfma_f32_16x16x32_bf16(a[m], wf[1][kc], acc[m][1], 0, 0, 0);
        }
    }
}

// ---------------------------------------------------------------------------
// Encoder GEMM: C[M x 128](bf16) = A[M x 128](fp32) @ W + bias
// ---------------------------------------------------------------------------
__global__ __launch_bounds__(256) void gemm_enc(const float* __restrict__ Ain,
                                                const unsigned short* __restrict__ Wpack,
                                                const float* __restrict__ bias,
                                                unsigned short* __restrict__ Cout, int M) {
    __shared__ unsigned short As[64 * 128];
    const int tid = threadIdx.x;
    const int lane = tid & 63;
    const int w = tid >> 6;
    const int row0 = blockIdx.x * 64;
    const int fr = lane & 15;
    const int fg = lane >> 4;

    short8v wf[2][4];
    load_wf(Wpack, w, fr, fg, wf);

    {
        const int r = tid >> 2;
        const int cg = tid & 3;
        const int row = row0 + r;
        char* lbase = (char*)As + r * 256;
        const float* Ap = Ain + (size_t)row * 128 + cg * 32;
#pragma unroll
        for (int i = 0; i < 4; ++i) {
            short8v v = {0, 0, 0, 0, 0, 0, 0, 0};
            if (row < M) {
                float4v p = *(const float4v*)(Ap + i * 8);
                float4v q = *(const float4v*)(Ap + i * 8 + 4);
                v[0] = (short)f2bf(p[0]); v[1] = (short)f2bf(p[1]);
                v[2] = (short)f2bf(p[2]); v[3] = (short)f2bf(p[3]);
                v[4] = (short)f2bf(q[0]); v[5] = (short)f2bf(q[1]);
                v[6] = (short)f2bf(q[2]); v[7] = (short)f2bf(q[3]);
            }
            int cb = (cg * 64 + i * 16) ^ ((r & 7) << 4);
            *(short8v*)(lbase + cb) = v;
        }
    }
    __syncthreads();

    float4v acc[4][2];
    mfma_tile(As, fr, fg, wf, acc);

#pragma unroll
    for (int t = 0; t < 2; ++t) {
        const int col = w * 32 + t * 16 + fr;
        const float bv = bias[col];
#pragma unroll
        for (int m = 0; m < 4; ++m)
#pragma unroll
            for (int q = 0; q < 4; ++q) {
                int row = row0 + m * 16 + fg * 4 + q;
                if (row < M) Cout[(size_t)row * 128 + col] = f2bf(acc[m][t][q] + bv);
            }
    }
}

// ---------------------------------------------------------------------------
// Fused GCN layer: xout = ((x + scatter_sum(x)) * invd) @ W + b
// Phase 1: per-block gather-aggregate of the 64-row tile directly into LDS
// (2 nodes per wave, bucket idxs preloaded + shfl-broadcast, x4 unroll).
// Phase 2: MFMA with fragment-packed W; bf16 store.
// ---------------------------------------------------------------------------
__global__ __launch_bounds__(256) void gcn_fused(const unsigned short* __restrict__ x,
                                                 const int* __restrict__ bucket,
                                                 const int* __restrict__ cnt,
                                                 const unsigned short* __restrict__ Wpack,
                                                 const float* __restrict__ bias,
                                                 unsigned short* __restrict__ xout,
                                                 int Nn) {
    __shared__ unsigned short As[64 * 128];
    const int tid = threadIdx.x;
    const int lane = tid & 63;
    const int w = tid >> 6;
    const int row0 = blockIdx.x * 64;
    const int fr = lane & 15;
    const int fg = lane >> 4;
    const int half = lane >> 5;
    const int hl = lane & 31;
    const int lbase = half << 5;

    short8v wf[2][4];
    load_wf(Wpack, w, fr, fg, wf);   // issue early; consumed after gather

    const uint32_t* hp = (const uint32_t*)x;

    // ---- phase 1: gather-aggregate 16 rows per wave (2 per pass) ----
#pragma unroll 1
    for (int p = 0; p < 8; ++p) {
        const int r = w * 16 + p * 2 + half;        // LDS row 0..63
        int node = row0 + r;
        if (node >= Nn) node = Nn - 1;              // clamped rows never stored

        const int c = cnt[node];
        const float id = 1.0f / (float)(c + 1);
        const int d = min(c, CAP);

        int idxv = 0;
        if (hl < d) idxv = bucket[(size_t)node * CAP + hl];

        const size_t rbase = (size_t)node * 64 + hl * 2;
        uint2 u = *(const uint2*)&hp[rbase];
        float a0 = bf2f((unsigned short)(u.x & 0xffff));
        float a1 = bf2f((unsigned short)(u.x >> 16));
        float a2 = bf2f((unsigned short)(u.y & 0xffff));
        float a3 = bf2f((unsigned short)(u.y >> 16));

        const int dmax = max(d, __shfl(d, lane ^ 32));
        const int dm32 = min(dmax, 32);
        for (int j = 0; j < dm32; j += 4) {
            int s0 = __shfl(idxv, lbase + j);
            int s1 = __shfl(idxv, lbase + j + 1);
            int s2 = __shfl(idxv, lbase + j + 2);
            int s3 = __shfl(idxv, lbase + j + 3);
            uint2 v0 = *(const uint2*)&hp[(size_t)s0 * 64 + hl * 2];
            uint2 v1 = *(const uint2*)&hp[(size_t)s1 * 64 + hl * 2];
            uint2 v2 = *(const uint2*)&hp[(size_t)s2 * 64 + hl * 2];
            uint2 v3 = *(const uint2*)&hp[(size_t)s3 * 64 + hl * 2];
            float m0 = (j + 0 < d) ? 1.f : 0.f;
            float m1 = (j + 1 < d) ? 1.f : 0.f;
            float m2 = (j + 2 < d) ? 1.f : 0.f;
            float m3 = (j + 3 < d) ? 1.f : 0.f;
            a0 = fmaf(m0, bf2f((unsigned short)(v0.x & 0xffff)), a0);
            a1 = fmaf(m0, bf2f((unsigned short)(v0.x >> 16)), a1);
            a2 = fmaf(m0, bf2f((unsigned short)(v0.y & 0xffff)), a2);
            a3 = fmaf(m0, bf2f((unsigned short)(v0.y >> 16)), a3);
            a0 = fmaf(m1, bf2f((unsigned short)(v1.x & 0xffff)), a0);
            a1 = fmaf(m1, bf2f((unsigned short)(v1.x >> 16)), a1);
            a2 = fmaf(m1, bf2f((unsigned short)(v1.y & 0xffff)), a2);
            a3 = fmaf(m1, bf2f((unsigned short)(v1.y >> 16)), a3);
            a0 = fmaf(m2, bf2f((unsigned short)(v2.x & 0xffff)), a0);
            a1 = fmaf(m2, bf2f((unsigned short)(v2.x >> 16)), a1);
            a2 = fmaf(m2, bf2f((unsigned short)(v2.y & 0xffff)), a2);
            a3 = fmaf(m2, bf2f((unsigned short)(v2.y >> 16)), a3);
            a0 = fmaf(m3, bf2f((unsigned short)(v3.x & 0xffff)), a0);
            a1 = fmaf(m3, bf2f((unsigned short)(v3.x >> 16)), a1);
            a2 = fmaf(m3, bf2f((unsigned short)(v3.y & 0xffff)), a2);
            a3 = fmaf(m3, bf2f((unsigned short)(v3.y >> 16)), a3);
        }
        for (int j = 32; j < d; ++j) {   // Poisson(6.4): effectively never
            int s = bucket[(size_t)node * CAP + j];
            uint2 v = *(const uint2*)&hp[(size_t)s * 64 + hl * 2];
            a0 += bf2f((unsigned short)(v.x & 0xffff));
            a1 += bf2f((unsigned short)(v.x >> 16));
            a2 += bf2f((unsigned short)(v.y & 0xffff));
            a3 += bf2f((unsigned short)(v.y >> 16));
        }

        a0 *= id; a1 *= id; a2 *= id; a3 *= id;
        uint2 o;
        o.x = (uint32_t)f2bf(a0) | ((uint32_t)f2bf(a1) << 16);
        o.y = (uint32_t)f2bf(a2) | ((uint32_t)f2bf(a3) << 16);
        *(uint2*)((char*)As + r * 256 + ((hl * 8) ^ ((r & 7) << 4))) = o;
    }
    __syncthreads();

    // ---- phase 2: MFMA + store ----
    float4v acc[4][2];
    mfma_tile(As, fr, fg, wf, acc);

#pragma unroll
    for (int t = 0; t < 2; ++t) {
        const int col = w * 32 + t * 16 + fr;
        const float bv = bias[col];
#pragma unroll
        for (int m = 0; m < 4; ++m)
#pragma unroll
            for (int q = 0; q < 4; ++q) {
                int row = row0 + m * 16 + fg * 4 + q;
                if (row < Nn) xout[(size_t)row * 128 + col] = f2bf(acc[m][t][q] + bv);
            }
    }
}

// ---------------------------------------------------------------------------
// Fused GateMLP: out = leaky(leaky(x@rW1+rb1)@rW2+rb2)
//                    * sigmoid(leaky(x@sW1+sb1)@sW2+sb2)
// One kernel; intermediates round-trip through a second LDS tile.
// ---------------------------------------------------------------------------
__global__ __launch_bounds__(256) void gate_fused(const unsigned short* __restrict__ x,
                                                  const unsigned short* __restrict__ wpack,
                                                  const float* __restrict__ rb1,
                                                  const float* __restrict__ rb2,
                                                  const float* __restrict__ sb1,
                                                  const float* __restrict__ sb2,
                                                  unsigned short* __restrict__ out, int M) {
    __shared__ unsigned short As[64 * 128];
    __shared__ unsigned short Bs[64 * 128];
    const int tid = threadIdx.x;
    const int lane = tid & 63;
    const int w = tid >> 6;
    const int row0 = blockIdx.x * 64;
    const int fr = lane & 15;
    const int fg = lane >> 4;

    // stage x tile
    {
        const int r = tid >> 2;
        const int cg = tid & 3;
        const int row = row0 + r;
        char* lbase = (char*)As + r * 256;
        const unsigned short* Ap = x + (size_t)row * 128 + cg * 32;
#pragma unroll
        for (int i = 0; i < 4; ++i) {
            short8v v = {0, 0, 0, 0, 0, 0, 0, 0};
            if (row < M) v = *(const short8v*)(Ap + i * 8);
            int cb = (cg * 64 + i * 16) ^ ((r & 7) << 4);
            *(short8v*)(lbase + cb) = v;
        }
    }
    __syncthreads();

    short8v wf[2][4];
    float4v acc[4][2];

    // helper macro: apply leaky(acc + bias[]) and write bf16 into Bs (swizzled)
#define WRITE_LDS_LEAKY(BIAS)                                                          \
    {                                                                                  \
        _Pragma("unroll") for (int t = 0; t < 2; ++t) {                                \
            const int col = w * 32 + t * 16 + fr;                                      \
            const float bv = (BIAS)[col];                                              \
            _Pragma("unroll") for (int m = 0; m < 4; ++m)                              \
                _Pragma("unroll") for (int q = 0; q < 4; ++q) {                        \
                    int r_ = m * 16 + fg * 4 + q;                                      \
                    float v_ = acc[m][t][q] + bv;                                      \
                    v_ = v_ > 0.f ? v_ : LEAK * v_;                                    \
                    *(unsigned short*)((char*)Bs + r_ * 256 +                          \
                                       ((col * 2) ^ ((r_ & 7) << 4))) = f2bf(v_);      \
                }                                                                      \
        }                                                                              \
    }

    // pass 1: u = leaky(x@rW1 + rb1) -> Bs
    load_wf(wpack + (size_t)5 * 16384, w, fr, fg, wf);
    mfma_tile(As, fr, fg, wf, acc);
    WRITE_LDS_LEAKY(rb1);
    __syncthreads();

    // pass 2: r = leaky(u@rW2 + rb2) -> registers
    load_wf(wpack + (size_t)6 * 16384, w, fr, fg, wf);
    float4v racc[4][2];
    mfma_tile(Bs, fr, fg, wf, racc);
#pragma unroll
    for (int t = 0; t < 2; ++t) {
        const float bv = rb2[w * 32 + t * 16 + fr];
#pragma unroll
        for (int m = 0; m < 4; ++m)
#pragma unroll
            for (int q = 0; q < 4; ++q) {
                float v = racc[m][t][q] + bv;
                racc[m][t][q] = v > 0.f ? v : LEAK * v;
            }
    }
    __syncthreads();   // all waves done reading Bs

    // pass 3: v = leaky(x@sW1 + sb1) -> Bs
    load_wf(wpack + (size_t)7 * 16384, w, fr, fg, wf);
    mfma_tile(As, fr, fg, wf, acc);
    WRITE_LDS_LEAKY(sb1);
    __syncthreads();

    // pass 4: g = sigmoid(v@sW2 + sb2); out = r * g
    load_wf(wpack + (size_t)8 * 16384, w, fr, fg, wf);
    mfma_tile(Bs, fr, fg, wf, acc);
#pragma unroll
    for (int t = 0; t < 2; ++t) {
        const int col = w * 32 + t * 16 + fr;
        const float bv = sb2[col];
#pragma unroll
        for (int m = 0; m < 4; ++m)
#pragma unroll
            for (int q = 0; q < 4; ++q) {
                int row = row0 + m * 16 + fg * 4 + q;
                if (row < M) {
                    float g = 1.f / (1.f + __expf(-(acc[m][t][q] + bv)));
                    out[(size_t)row * 128 + col] = f2bf(g * racc[m][t][q]);
                }
            }
    }
#undef WRITE_LDS_LEAKY
}

// ---------------------------------------------------------------------------
// Exclusive-scan num_atoms -> goff[G+1]. Single block, G <= 1024.
// ---------------------------------------------------------------------------
__global__ void scan_atoms(const int* __restrict__ na, int* __restrict__ goff, int G_) {
    __shared__ int sh[1024];
    int t = threadIdx.x;
    int v = (t < G_) ? na[t] : 0;
    sh[t] = v;
    __syncthreads();
    for (int ofs = 1; ofs < 1024; ofs <<= 1) {
        int u = (t >= ofs) ? sh[t - ofs] : 0;
        __syncthreads();
        sh[t] += u;
        __syncthreads();
    }
    if (t == 0) goff[0] = 0;
    if (t < G_) goff[t + 1] = sh[t];
}

// ---------------------------------------------------------------------------
// Graph mean-pool from bf16 x. 2 graphs per 256-thread block.
// ---------------------------------------------------------------------------
__global__ void pool(const unsigned short* __restrict__ x, const int* __restrict__ goff,
                     float* __restrict__ gattr, int G_) {
    int g = blockIdx.x * 2 + (threadIdx.x >> 7);
    if (g >= G_) return;
    int d = threadIdx.x & 127;
    int a0 = goff[g], a1 = goff[g + 1];
    float s = 0.f;
    for (int a = a0; a < a1; ++a) s += bf2f(x[(size_t)a * 128 + d]);
    float c = (float)max(a1 - a0, 1);
    gattr[(size_t)g * 128 + d] = s / c;
}

// ---------------------------------------------------------------------------
// Final: out[g][c] = gattr[g] @ fin_W[:,c] + fin_b[c]   (C = 10), fp32.
// ---------------------------------------------------------------------------
__global__ void final_gemm(const float* __restrict__ gattr, const float* __restrict__ fW,
                           const float* __restrict__ fb, float* __restrict__ out,
                           int G_, int C_) {
    int i = blockIdx.x * 256 + threadIdx.x;
    if (i >= G_ * C_) return;
    int g = i / C_, c = i % C_;
    const float* row = gattr + (size_t)g * 128;
    float s = fb[c];
    for (int k = 0; k < 128; ++k) s = fmaf(row[k], fW[k * C_ + c], s);
    out[i] = s;
}

// ---------------------------------------------------------------------------
extern "C" void kernel_launch(void* const* d_in, const int* in_sizes, int n_in,
                              void* d_out, int out_size, void* d_ws, size_t ws_size,
                              hipStream_t stream) {
    const float* node_attr = (const float*)d_in[0];
    const int* edge_index  = (const int*)d_in[1];
    const int* num_atoms   = (const int*)d_in[2];
    const float* enc_W = (const float*)d_in[3];
    const float* enc_b = (const float*)d_in[4];
    const float* gcn_W = (const float*)d_in[5];
    const float* gcn_b = (const float*)d_in[6];
    const float* r_W1 = (const float*)d_in[7];
    const float* r_b1 = (const float*)d_in[8];
    const float* r_W2 = (const float*)d_in[9];
    const float* r_b2 = (const float*)d_in[10];
    const float* s_W1 = (const float*)d_in[11];
    const float* s_b1 = (const float*)d_in[12];
    const float* s_W2 = (const float*)d_in[13];
    const float* s_b2 = (const float*)d_in[14];
    const float* fin_W = (const float*)d_in[15];
    const float* fin_b = (const float*)d_in[16];
    float* out = (float*)d_out;

    const int N_ = in_sizes[0] / 128;
    const int E_ = in_sizes[1] / 2;
    const int G_ = in_sizes[2];
    const int C_ = in_sizes[16];

    size_t off = 0;
    auto alloc = [&](size_t bytes) -> void* {
        void* p = (char*)d_ws + off;
        off += (bytes + 255) & ~(size_t)255;
        return p;
    };
    unsigned short* bx = (unsigned short*)alloc((size_t)N_ * 128 * 2);
    unsigned short* bh = (unsigned short*)alloc((size_t)N_ * 128 * 2);
    int* bucket = (int*)alloc((size_t)N_ * CAP * 4);
    int* cnt    = (int*)alloc((size_t)N_ * 4);
    unsigned short* wpack = (unsigned short*)alloc((size_t)9 * 16384 * 2);
    int* goff   = (int*)alloc((size_t)(G_ + 1) * 4);
    float* gattr = (float*)alloc((size_t)G_ * 128 * 4);
    (void)ws_size; (void)n_in; (void)out_size;

    const int gemm_grid = (N_ + 63) / 64;

    // 1. degree buckets + weight packing + graph offsets
    hipMemsetAsync(cnt, 0, (size_t)N_ * 4, stream);
    build_buckets<<<(E_ / 2 + 255) / 256, 256, 0, stream>>>(edge_index, E_, cnt, bucket);
    pack_w<<<72, 256, 0, stream>>>(enc_W, gcn_W, r_W1, r_W2, s_W1, s_W2, wpack);
    scan_atoms<<<1, 1024, 0, stream>>>(num_atoms, goff, G_);

    // 2. encoder (fp32 in -> bf16 out)
    gemm_enc<<<gemm_grid, 256, 0, stream>>>(node_attr, wpack, enc_b, bx, N_);

    // 3. fused GCN layers (aggregate-then-GEMM, ping-pong bx<->bh)
    unsigned short* cur = bx;
    unsigned short* nxt = bh;
    for (int l = 0; l < 4; ++l) {
        gcn_fused<<<gemm_grid, 256, 0, stream>>>(cur, bucket, cnt,
                                                 wpack + (size_t)(1 + l) * 16384,
                                                 gcn_b + (size_t)l * 128, nxt, N_);
        unsigned short* t = cur; cur = nxt; nxt = t;
    }

    // 4. fused GateMLP: cur -> nxt
    gate_fused<<<gemm_grid, 256, 0, stream>>>(cur, wpack, r_b1, r_b2, s_b1, s_b2, nxt, N_);

    // 5. pool + final
    pool<<<(G_ + 1) / 2, 256, 0, stream>>>(nxt, goff, gattr, G_);
    final_gemm<<<(G_ * C_ + 255) / 256, 256, 0, stream>>>(gattr, fin_W, fin_b, out, G_, C_);
}

// Round 5
// 297.786 us; speedup vs baseline: 4.0169x; 1.1717x over previous
//
#include <hip/hip_runtime.h>
#include <hip/hip_bf16.h>
#include <cstddef>
#include <cstdint>

#define CAP 40
#define LEAK 0.01f

typedef __attribute__((ext_vector_type(8))) short short8v;
typedef __attribute__((ext_vector_type(4))) float float4v;

__device__ __forceinline__ unsigned short f2bf(float f) {
    uint32_t u = __float_as_uint(f);
    uint32_t r = (u + 0x7FFFu + ((u >> 16) & 1u)) >> 16;   // RNE
    return (unsigned short)r;
}
__device__ __forceinline__ float bf2f(unsigned short s) {
    return __uint_as_float(((uint32_t)s) << 16);
}

// ---------------------------------------------------------------------------
// Bucket build, 4 edges/thread (int4 loads): append src to dst's bucket.
// cnt ends as in-degree(dst). 4 atomics in flight per thread.
// ---------------------------------------------------------------------------
__global__ void build_buckets(const int* __restrict__ ei, int E_,
                              int* __restrict__ cnt, int* __restrict__ bucket) {
    int e = (blockIdx.x * 256 + threadIdx.x) * 4;
    if (e >= E_) return;
    if (e + 4 <= E_) {
        int4 d4 = *(const int4*)&ei[e];
        int4 s4 = *(const int4*)&ei[(size_t)E_ + e];
        int p0 = atomicAdd(&cnt[d4.x], 1);
        int p1 = atomicAdd(&cnt[d4.y], 1);
        int p2 = atomicAdd(&cnt[d4.z], 1);
        int p3 = atomicAdd(&cnt[d4.w], 1);
        if (p0 < CAP) bucket[(size_t)d4.x * CAP + p0] = s4.x;
        if (p1 < CAP) bucket[(size_t)d4.y * CAP + p1] = s4.y;
        if (p2 < CAP) bucket[(size_t)d4.z * CAP + p2] = s4.z;
        if (p3 < CAP) bucket[(size_t)d4.w * CAP + p3] = s4.w;
    } else {
        for (; e < E_; ++e) {
            int d = ei[e], s = ei[(size_t)E_ + e];
            int p = atomicAdd(&cnt[d], 1);
            if (p < CAP) bucket[(size_t)d * CAP + p] = s;
        }
    }
}

// ---------------------------------------------------------------------------
// Pack 9 fp32 [128x128] weight matrices into bf16 MFMA-fragment order:
// p[m][((kc*4+fg)*128 + n)*8 + j] = bf16(W_m[(kc*32+fg*8+j)*128 + n])
// ---------------------------------------------------------------------------
__global__ void pack_w(const float* __restrict__ enc, const float* __restrict__ gcn,
                       const float* __restrict__ rw1, const float* __restrict__ rw2,
                       const float* __restrict__ sw1, const float* __restrict__ sw2,
                       unsigned short* __restrict__ p) {
    int m = blockIdx.x >> 3;
    int idx = (blockIdx.x & 7) * 256 + threadIdx.x;   // 0..2047
    const float* W;
    switch (m) {
        case 0: W = enc; break;
        case 1: case 2: case 3: case 4: W = gcn + (size_t)(m - 1) * 16384; break;
        case 5: W = rw1; break;
        case 6: W = rw2; break;
        case 7: W = sw1; break;
        default: W = sw2; break;
    }
    int n = idx & 127;
    int fg = (idx >> 7) & 3;
    int kc = idx >> 9;
    short8v v;
#pragma unroll
    for (int j = 0; j < 8; ++j)
        v[j] = (short)f2bf(W[(size_t)(kc * 32 + fg * 8 + j) * 128 + n]);
    *(short8v*)(p + (size_t)m * 16384 + (size_t)idx * 8) = v;
}

// ---------------------------------------------------------------------------
// Shared MFMA helpers. LDS tile layout: 64 rows x 128 bf16 cols, 256 B/row,
// byte offset within row XOR-swizzled by ((row&7)<<4).
// A-frag {m=lane&15, k=(lane>>4)*8+j}; B-frag {n=lane&15, k=(lane>>4)*8+j};
// C/D {col=lane&15, row=(lane>>4)*4+reg}.
// ---------------------------------------------------------------------------
__device__ __forceinline__ void load_wf(const unsigned short* __restrict__ Wpack,
                                        int w, int fr, int fg, short8v wf[2][4]) {
    const short8v* Wp = (const short8v*)Wpack;
#pragma unroll
    for (int t = 0; t < 2; ++t)
#pragma unroll
        for (int kc = 0; kc < 4; ++kc)
            wf[t][kc] = Wp[(kc * 4 + fg) * 128 + w * 32 + t * 16 + fr];
}

__device__ __forceinline__ void mfma_tile(const unsigned short* As, int fr, int fg,
                                          const short8v wf[2][4], float4v acc[4][2]) {
#pragma unroll
    for (int m = 0; m < 4; ++m) {
        acc[m][0] = (float4v){0.f, 0.f, 0.f, 0.f};
        acc[m][1] = (float4v){0.f, 0.f, 0.f, 0.f};
    }
#pragma unroll
    for (int kc = 0; kc < 4; ++kc) {
        short8v a[4];
#pragma unroll
        for (int m = 0; m < 4; ++m) {
            int row = m * 16 + fr;
            int cb = (kc * 64 + fg * 16) ^ ((row & 7) << 4);
            a[m] = *(const short8v*)((const char*)As + row * 256 + cb);
        }
#pragma unroll
        for (int m = 0; m < 4; ++m) {
            acc[m][0] = __builtin_amdgcn_mfma_f32_16x16x32_bf16(a[m], wf[0][kc], acc[m][0], 0, 0, 0);
            acc[m][1] = __builtin_amdgcn_mfma_f32_16x16x32_bf16(a[m], wf[1][kc], acc[m][1], 0, 0, 0);
        }
    }
}

// ---------------------------------------------------------------------------
// Encoder GEMM: C[M x 128](bf16) = A[M x 128](fp32) @ W + bias
// ---------------------------------------------------------------------------
__global__ __launch_bounds__(256) void gemm_enc(const float* __restrict__ Ain,
                                                const unsigned short* __restrict__ Wpack,
                                                const float* __restrict__ bias,
                                                unsigned short* __restrict__ Cout, int M) {
    __shared__ unsigned short As[64 * 128];
    const int tid = threadIdx.x;
    const int lane = tid & 63;
    const int w = tid >> 6;
    const int row0 = blockIdx.x * 64;
    const int fr = lane & 15;
    const int fg = lane >> 4;

    short8v wf[2][4];
    load_wf(Wpack, w, fr, fg, wf);

    {
        const int r = tid >> 2;
        const int cg = tid & 3;
        const int row = row0 + r;
        char* lbase = (char*)As + r * 256;
        const float* Ap = Ain + (size_t)row * 128 + cg * 32;
#pragma unroll
        for (int i = 0; i < 4; ++i) {
            short8v v = {0, 0, 0, 0, 0, 0, 0, 0};
            if (row < M) {
                float4v p = *(const float4v*)(Ap + i * 8);
                float4v q = *(const float4v*)(Ap + i * 8 + 4);
                v[0] = (short)f2bf(p[0]); v[1] = (short)f2bf(p[1]);
                v[2] = (short)f2bf(p[2]); v[3] = (short)f2bf(p[3]);
                v[4] = (short)f2bf(q[0]); v[5] = (short)f2bf(q[1]);
                v[6] = (short)f2bf(q[2]); v[7] = (short)f2bf(q[3]);
            }
            int cb = (cg * 64 + i * 16) ^ ((r & 7) << 4);
            *(short8v*)(lbase + cb) = v;
        }
    }
    __syncthreads();

    float4v acc[4][2];
    mfma_tile(As, fr, fg, wf, acc);

#pragma unroll
    for (int t = 0; t < 2; ++t) {
        const int col = w * 32 + t * 16 + fr;
        const float bv = bias[col];
#pragma unroll
        for (int m = 0; m < 4; ++m)
#pragma unroll
            for (int q = 0; q < 4; ++q) {
                int row = row0 + m * 16 + fg * 4 + q;
                if (row < M) Cout[(size_t)row * 128 + col] = f2bf(acc[m][t][q] + bv);
            }
    }
}

// ---------------------------------------------------------------------------
// accumulate 8 bf16 (uint4) into 8 f32, predicated by m
// ---------------------------------------------------------------------------
__device__ __forceinline__ void acc8(float a[8], uint4 v, float m) {
    a[0] = fmaf(m, bf2f((unsigned short)(v.x & 0xffff)), a[0]);
    a[1] = fmaf(m, bf2f((unsigned short)(v.x >> 16)), a[1]);
    a[2] = fmaf(m, bf2f((unsigned short)(v.y & 0xffff)), a[2]);
    a[3] = fmaf(m, bf2f((unsigned short)(v.y >> 16)), a[3]);
    a[4] = fmaf(m, bf2f((unsigned short)(v.z & 0xffff)), a[4]);
    a[5] = fmaf(m, bf2f((unsigned short)(v.z >> 16)), a[5]);
    a[6] = fmaf(m, bf2f((unsigned short)(v.w & 0xffff)), a[6]);
    a[7] = fmaf(m, bf2f((unsigned short)(v.w >> 16)), a[7]);
}

// ---------------------------------------------------------------------------
// Fused GCN layer: xout = ((x + scatter_sum(x)) * invd) @ W + b
// Gather phase: 16 lanes per row (uint4 = 16B/lane), 4 rows per pass, 4
// fully-unrolled passes. cnt + own-rows + ALL neighbor indices prefetched
// unconditionally up-front (poison-safe via clamp + FMA mask) so the only
// dependent loads are the gathers themselves, unrolled x4.
// ---------------------------------------------------------------------------
__global__ __launch_bounds__(256) void gcn_fused(const unsigned short* __restrict__ x,
                                                 const int* __restrict__ bucket,
                                                 const int* __restrict__ cnt,
                                                 const unsigned short* __restrict__ Wpack,
                                                 const float* __restrict__ bias,
                                                 unsigned short* __restrict__ xout,
                                                 int Nn) {
    __shared__ unsigned short As[64 * 128];
    const int tid = threadIdx.x;
    const int lane = tid & 63;
    const int w = tid >> 6;
    const int row0 = blockIdx.x * 64;
    const int fr = lane & 15;
    const int fg = lane >> 4;
    const int l16 = lane & 15;
    const int g = lane >> 4;          // 16-lane group 0..3
    const int gl = lane & 48;         // g*16
    const char* xb = (const char*)x;

    // ---- up-front prefetch: cnt (1 load), own rows (4), neighbor idx (4) ----
    int cfull = 0;
    if (lane < 16) {
        int gn = row0 + w * 16 + lane;
        if (gn >= Nn) gn = Nn - 1;
        cfull = cnt[gn];
    }
    uint4 own[4];
    int2 pre[4];      // pass p: slots 2*l16, 2*l16+1 of node 4p+g
#pragma unroll
    for (int p = 0; p < 4; ++p) {
        int gn = row0 + w * 16 + p * 4 + g;
        if (gn >= Nn) gn = Nn - 1;
        own[p] = *(const uint4*)(xb + (size_t)gn * 256 + l16 * 16);
        pre[p] = *(const int2*)&bucket[(size_t)gn * CAP + 2 * l16];   // unconditional
    }

    // ---- 4 gather passes, fully unrolled (static own/pre indexing) ----
#pragma unroll
    for (int p = 0; p < 4; ++p) {
        const int n = p * 4 + g;          // node within wave tile, 0..15
        const int r = w * 16 + n;         // LDS row
        const int dfull = __shfl(cfull, n);
        const float id = 1.0f / (float)(dfull + 1);
        const int d = min(dfull, CAP);
        const int dm = min(d, 32);

        float a[8];
        acc8(a, own[p], 0.f);   // init: a = 0*garbage... (set below)
        {
            uint4 o = own[p];
            a[0] = bf2f((unsigned short)(o.x & 0xffff));
            a[1] = bf2f((unsigned short)(o.x >> 16));
            a[2] = bf2f((unsigned short)(o.y & 0xffff));
            a[3] = bf2f((unsigned short)(o.y >> 16));
            a[4] = bf2f((unsigned short)(o.z & 0xffff));
            a[5] = bf2f((unsigned short)(o.z >> 16));
            a[6] = bf2f((unsigned short)(o.w & 0xffff));
            a[7] = bf2f((unsigned short)(o.w >> 16));
        }

        for (int j = 0; j < dm; j += 4) {
            int sl = gl + (j >> 1);
            int s0 = __shfl(pre[p].x, sl);
            int s1 = __shfl(pre[p].y, sl);
            int s2 = __shfl(pre[p].x, sl + 1);
            int s3 = __shfl(pre[p].y, sl + 1);
            // clamp: slots >= d hold poison/stale bits; masked at FMA anyway
            s0 = min(max(s0, 0), Nn - 1);
            s1 = min(max(s1, 0), Nn - 1);
            s2 = min(max(s2, 0), Nn - 1);
            s3 = min(max(s3, 0), Nn - 1);
            uint4 v0 = *(const uint4*)(xb + (size_t)s0 * 256 + l16 * 16);
            uint4 v1 = *(const uint4*)(xb + (size_t)s1 * 256 + l16 * 16);
            uint4 v2 = *(const uint4*)(xb + (size_t)s2 * 256 + l16 * 16);
            uint4 v3 = *(const uint4*)(xb + (size_t)s3 * 256 + l16 * 16);
            acc8(a, v0, (j + 0 < d) ? 1.f : 0.f);
            acc8(a, v1, (j + 1 < d) ? 1.f : 0.f);
            acc8(a, v2, (j + 2 < d) ? 1.f : 0.f);
            acc8(a, v3, (j + 3 < d) ? 1.f : 0.f);
        }
        if (d > 32) {                      // Poisson(6.4): effectively never
            int gn = row0 + r; if (gn >= Nn) gn = Nn - 1;
            for (int j = 32; j < d; ++j) {
                int s = bucket[(size_t)gn * CAP + j];
                uint4 v = *(const uint4*)(xb + (size_t)s * 256 + l16 * 16);
                acc8(a, v, 1.f);
            }
        }

#pragma unroll
        for (int i = 0; i < 8; ++i) a[i] *= id;
        uint4 o;
        o.x = (uint32_t)f2bf(a[0]) | ((uint32_t)f2bf(a[1]) << 16);
        o.y = (uint32_t)f2bf(a[2]) | ((uint32_t)f2bf(a[3]) << 16);
        o.z = (uint32_t)f2bf(a[4]) | ((uint32_t)f2bf(a[5]) << 16);
        o.w = (uint32_t)f2bf(a[6]) | ((uint32_t)f2bf(a[7]) << 16);
        *(uint4*)((char*)As + r * 256 + ((l16 * 16) ^ ((r & 7) << 4))) = o;
    }

    // W fragments: issued now, fly during the barrier (L2-hot)
    short8v wf[2][4];
    load_wf(Wpack, w, fr, fg, wf);
    __syncthreads();

    // ---- MFMA + store ----
    float4v acc[4][2];
    mfma_tile(As, fr, fg, wf, acc);

#pragma unroll
    for (int t = 0; t < 2; ++t) {
        const int col = w * 32 + t * 16 + fr;
        const float bv = bias[col];
#pragma unroll
        for (int m = 0; m < 4; ++m)
#pragma unroll
            for (int q = 0; q < 4; ++q) {
                int row = row0 + m * 16 + fg * 4 + q;
                if (row < Nn) xout[(size_t)row * 128 + col] = f2bf(acc[m][t][q] + bv);
            }
    }
}

// ---------------------------------------------------------------------------
// Fused GateMLP: out = leaky(leaky(x@rW1+rb1)@rW2+rb2)
//                    * sigmoid(leaky(x@sW1+sb1)@sW2+sb2)
// ---------------------------------------------------------------------------
__global__ __launch_bounds__(256) void gate_fused(const unsigned short* __restrict__ x,
                                                  const unsigned short* __restrict__ wpack,
                                                  const float* __restrict__ rb1,
                                                  const float* __restrict__ rb2,
                                                  const float* __restrict__ sb1,
                                                  const float* __restrict__ sb2,
                                                  unsigned short* __restrict__ out, int M) {
    __shared__ unsigned short As[64 * 128];
    __shared__ unsigned short Bs[64 * 128];
    const int tid = threadIdx.x;
    const int lane = tid & 63;
    const int w = tid >> 6;
    const int row0 = blockIdx.x * 64;
    const int fr = lane & 15;
    const int fg = lane >> 4;

    // stage x tile
    {
        const int r = tid >> 2;
        const int cg = tid & 3;
        const int row = row0 + r;
        char* lbase = (char*)As + r * 256;
        const unsigned short* Ap = x + (size_t)row * 128 + cg * 32;
#pragma unroll
        for (int i = 0; i < 4; ++i) {
            short8v v = {0, 0, 0, 0, 0, 0, 0, 0};
            if (row < M) v = *(const short8v*)(Ap + i * 8);
            int cb = (cg * 64 + i * 16) ^ ((r & 7) << 4);
            *(short8v*)(lbase + cb) = v;
        }
    }
    __syncthreads();

    short8v wf[2][4];
    float4v acc[4][2];

#define WRITE_LDS_LEAKY(BIAS)                                                          \
    {                                                                                  \
        _Pragma("unroll") for (int t = 0; t < 2; ++t) {                                \
            const int col = w * 32 + t * 16 + fr;                                      \
            const float bv = (BIAS)[col];                                              \
            _Pragma("unroll") for (int m = 0; m < 4; ++m)                              \
                _Pragma("unroll") for (int q = 0; q < 4; ++q) {                        \
                    int r_ = m * 16 + fg * 4 + q;                                      \
                    float v_ = acc[m][t][q] + bv;                                      \
                    v_ = v_ > 0.f ? v_ : LEAK * v_;                                    \
                    *(unsigned short*)((char*)Bs + r_ * 256 +                          \
                                       ((col * 2) ^ ((r_ & 7) << 4))) = f2bf(v_);      \
                }                                                                      \
        }                                                                              \
    }

    // pass 1: u = leaky(x@rW1 + rb1) -> Bs
    load_wf(wpack + (size_t)5 * 16384, w, fr, fg, wf);
    mfma_tile(As, fr, fg, wf, acc);
    WRITE_LDS_LEAKY(rb1);
    __syncthreads();

    // pass 2: r = leaky(u@rW2 + rb2) -> registers
    load_wf(wpack + (size_t)6 * 16384, w, fr, fg, wf);
    float4v racc[4][2];
    mfma_tile(Bs, fr, fg, wf, racc);
#pragma unroll
    for (int t = 0; t < 2; ++t) {
        const float bv = rb2[w * 32 + t * 16 + fr];
#pragma unroll
        for (int m = 0; m < 4; ++m)
#pragma unroll
            for (int q = 0; q < 4; ++q) {
                float v = racc[m][t][q] + bv;
                racc[m][t][q] = v > 0.f ? v : LEAK * v;
            }
    }
    __syncthreads();

    // pass 3: v = leaky(x@sW1 + sb1) -> Bs
    load_wf(wpack + (size_t)7 * 16384, w, fr, fg, wf);
    mfma_tile(As, fr, fg, wf, acc);
    WRITE_LDS_LEAKY(sb1);
    __syncthreads();

    // pass 4: g = sigmoid(v@sW2 + sb2); out = r * g
    load_wf(wpack + (size_t)8 * 16384, w, fr, fg, wf);
    mfma_tile(Bs, fr, fg, wf, acc);
#pragma unroll
    for (int t = 0; t < 2; ++t) {
        const int col = w * 32 + t * 16 + fr;
        const float bv = sb2[col];
#pragma unroll
        for (int m = 0; m < 4; ++m)
#pragma unroll
            for (int q = 0; q < 4; ++q) {
                int row = row0 + m * 16 + fg * 4 + q;
                if (row < M) {
                    float gg = 1.f / (1.f + __expf(-(acc[m][t][q] + bv)));
                    out[(size_t)row * 128 + col] = f2bf(gg * racc[m][t][q]);
                }
            }
    }
#undef WRITE_LDS_LEAKY
}

// ---------------------------------------------------------------------------
// Exclusive-scan num_atoms -> goff[G+1]. Single block, G <= 1024.
// ---------------------------------------------------------------------------
__global__ void scan_atoms(const int* __restrict__ na, int* __restrict__ goff, int G_) {
    __shared__ int sh[1024];
    int t = threadIdx.x;
    int v = (t < G_) ? na[t] : 0;
    sh[t] = v;
    __syncthreads();
    for (int ofs = 1; ofs < 1024; ofs <<= 1) {
        int u = (t >= ofs) ? sh[t - ofs] : 0;
        __syncthreads();
        sh[t] += u;
        __syncthreads();
    }
    if (t == 0) goff[0] = 0;
    if (t < G_) goff[t + 1] = sh[t];
}

// ---------------------------------------------------------------------------
// Graph mean-pool from bf16 x. 2 graphs per 256-thread block, x4 unrolled
// independent partial sums.
// ---------------------------------------------------------------------------
__global__ void pool(const unsigned short* __restrict__ x, const int* __restrict__ goff,
                     float* __restrict__ gattr, int G_) {
    int g = blockIdx.x * 2 + (threadIdx.x >> 7);
    if (g >= G_) return;
    int d = threadIdx.x & 127;
    int a0 = goff[g], a1 = goff[g + 1];
    float s0 = 0.f, s1 = 0.f, s2 = 0.f, s3 = 0.f;
    int a = a0;
    for (; a + 4 <= a1; a += 4) {
        s0 += bf2f(x[(size_t)(a + 0) * 128 + d]);
        s1 += bf2f(x[(size_t)(a + 1) * 128 + d]);
        s2 += bf2f(x[(size_t)(a + 2) * 128 + d]);
        s3 += bf2f(x[(size_t)(a + 3) * 128 + d]);
    }
    for (; a < a1; ++a) s0 += bf2f(x[(size_t)a * 128 + d]);
    float s = (s0 + s1) + (s2 + s3);
    float c = (float)max(a1 - a0, 1);
    gattr[(size_t)g * 128 + d] = s / c;
}

// ---------------------------------------------------------------------------
// Final: out[g][c] = gattr[g] @ fin_W[:,c] + fin_b[c]   (C = 10), fp32.
// ---------------------------------------------------------------------------
__global__ void final_gemm(const float* __restrict__ gattr, const float* __restrict__ fW,
                           const float* __restrict__ fb, float* __restrict__ out,
                           int G_, int C_) {
    int i = blockIdx.x * 256 + threadIdx.x;
    if (i >= G_ * C_) return;
    int g = i / C_, c = i % C_;
    const float* row = gattr + (size_t)g * 128;
    float s = fb[c];
    for (int k = 0; k < 128; ++k) s = fmaf(row[k], fW[k * C_ + c], s);
    out[i] = s;
}

// ---------------------------------------------------------------------------
extern "C" void kernel_launch(void* const* d_in, const int* in_sizes, int n_in,
                              void* d_out, int out_size, void* d_ws, size_t ws_size,
                              hipStream_t stream) {
    const float* node_attr = (const float*)d_in[0];
    const int* edge_index  = (const int*)d_in[1];
    const int* num_atoms   = (const int*)d_in[2];
    const float* enc_W = (const float*)d_in[3];
    const float* enc_b = (const float*)d_in[4];
    const float* gcn_W = (const float*)d_in[5];
    const float* gcn_b = (const float*)d_in[6];
    const float* r_W1 = (const float*)d_in[7];
    const float* r_b1 = (const float*)d_in[8];
    const float* r_W2 = (const float*)d_in[9];
    const float* r_b2 = (const float*)d_in[10];
    const float* s_W1 = (const float*)d_in[11];
    const float* s_b1 = (const float*)d_in[12];
    const float* s_W2 = (const float*)d_in[13];
    const float* s_b2 = (const float*)d_in[14];
    const float* fin_W = (const float*)d_in[15];
    const float* fin_b = (const float*)d_in[16];
    float* out = (float*)d_out;

    const int N_ = in_sizes[0] / 128;
    const int E_ = in_sizes[1] / 2;
    const int G_ = in_sizes[2];
    const int C_ = in_sizes[16];

    size_t off = 0;
    auto alloc = [&](size_t bytes) -> void* {
        void* p = (char*)d_ws + off;
        off += (bytes + 255) & ~(size_t)255;
        return p;
    };
    unsigned short* bx = (unsigned short*)alloc((size_t)N_ * 128 * 2);
    unsigned short* bh = (unsigned short*)alloc((size_t)N_ * 128 * 2);
    int* bucket = (int*)alloc((size_t)N_ * CAP * 4);
    int* cnt    = (int*)alloc((size_t)N_ * 4);
    unsigned short* wpack = (unsigned short*)alloc((size_t)9 * 16384 * 2);
    int* goff   = (int*)alloc((size_t)(G_ + 1) * 4);
    float* gattr = (float*)alloc((size_t)G_ * 128 * 4);
    (void)ws_size; (void)n_in; (void)out_size;

    const int gemm_grid = (N_ + 63) / 64;

    // 1. degree buckets + weight packing + graph offsets
    hipMemsetAsync(cnt, 0, (size_t)N_ * 4, stream);
    build_buckets<<<(E_ / 4 + 255) / 256, 256, 0, stream>>>(edge_index, E_, cnt, bucket);
    pack_w<<<72, 256, 0, stream>>>(enc_W, gcn_W, r_W1, r_W2, s_W1, s_W2, wpack);
    scan_atoms<<<1, 1024, 0, stream>>>(num_atoms, goff, G_);

    // 2. encoder (fp32 in -> bf16 out)
    gemm_enc<<<gemm_grid, 256, 0, stream>>>(node_attr, wpack, enc_b, bx, N_);

    // 3. fused GCN layers (aggregate-then-GEMM, ping-pong bx<->bh)
    unsigned short* cur = bx;
    unsigned short* nxt = bh;
    for (int l = 0; l < 4; ++l) {
        gcn_fused<<<gemm_grid, 256, 0, stream>>>(cur, bucket, cnt,
                                                 wpack + (size_t)(1 + l) * 16384,
                                                 gcn_b + (size_t)l * 128, nxt, N_);
        unsigned short* t = cur; cur = nxt; nxt = t;
    }

    // 4. fused GateMLP: cur -> nxt
    gate_fused<<<gemm_grid, 256, 0, stream>>>(cur, wpack, r_b1, r_b2, s_b1, s_b2, nxt, N_);

    // 5. pool + final
    pool<<<(G_ + 1) / 2, 256, 0, stream>>>(nxt, goff, gattr, G_);
    final_gemm<<<(G_ * C_ + 255) / 256, 256, 0, stream>>>(gattr, fin_W, fin_b, out, G_, C_);
}